// Round 25
// baseline (90.354 us; speedup 1.0000x reference)
//
#include <hip/hip_runtime.h>
#include <hip/hip_bf16.h>
#include <stdint.h>

#define N_TOK 8192
#define D 128
#define QTILES (N_TOK / 16)    // 512
#define KVB 64                 // kv rows per staged tile
#define KVTILES (N_TOK / KVB)  // 128
#define LOG2E 1.4426950408889634f

typedef __attribute__((ext_vector_type(8))) short short8;      // 8x16b frag
typedef __attribute__((ext_vector_type(4))) short short4v;     // 4x16b (8B)
typedef __attribute__((ext_vector_type(4))) float f32x4;       // MFMA accum
typedef __attribute__((ext_vector_type(8))) _Float16 half8;    // f16x8 frag
typedef __attribute__((ext_vector_type(4))) _Float16 half4;    // 4 f16 (8B)
typedef __attribute__((ext_vector_type(2))) __fp16 fp16x2;     // cvt_pkrtz ret
typedef __attribute__((ext_vector_type(2))) unsigned int uint2v;

__device__ __forceinline__ f32x4 zero4() {
    f32x4 z; z[0] = 0.f; z[1] = 0.f; z[2] = 0.f; z[3] = 0.f; return z;
}
__device__ __forceinline__ float ex2(float x) {
    return __builtin_amdgcn_exp2f(x);   // raw v_exp_f32 (2^x), no libm wrapper
}
__device__ __forceinline__ float max16(const f32x4* s) {
    // 16-value max via v_max3 fusion (nested triples)
    float a = fmaxf(fmaxf(s[0][0], s[0][1]), s[0][2]);
    float b = fmaxf(fmaxf(s[0][3], s[1][0]), s[1][1]);
    float c = fmaxf(fmaxf(s[1][2], s[1][3]), s[2][0]);
    float d = fmaxf(fmaxf(s[2][1], s[2][2]), s[2][3]);
    float e = fmaxf(fmaxf(s[3][0], s[3][1]), s[3][2]);
    return fmaxf(fmaxf(fmaxf(a, b), c), fmaxf(fmaxf(d, e), s[3][3]));
}

// ---- cross-lane 4-group reductions (lanes l, l^16, l^32, l^48) -------------
#if __has_builtin(__builtin_amdgcn_permlane16_swap) && __has_builtin(__builtin_amdgcn_permlane32_swap)
#define HAVE_PERMLANE 1
__device__ __forceinline__ float red16_max(float x) {
    union { float f; unsigned u; } c; c.f = x;
    uint2v r = __builtin_amdgcn_permlane16_swap(c.u, c.u, false, false);
    union { unsigned u; float f; } a, b; a.u = r[0]; b.u = r[1];
    return fmaxf(a.f, b.f);
}
__device__ __forceinline__ float red32_max(float x) {
    union { float f; unsigned u; } c; c.f = x;
    uint2v r = __builtin_amdgcn_permlane32_swap(c.u, c.u, false, false);
    union { unsigned u; float f; } a, b; a.u = r[0]; b.u = r[1];
    return fmaxf(a.f, b.f);
}
__device__ __forceinline__ float red16_sum(float x) {
    union { float f; unsigned u; } c; c.f = x;
    uint2v r = __builtin_amdgcn_permlane16_swap(c.u, c.u, false, false);
    union { unsigned u; float f; } a, b; a.u = r[0]; b.u = r[1];
    return a.f + b.f;
}
__device__ __forceinline__ float red32_sum(float x) {
    union { float f; unsigned u; } c; c.f = x;
    uint2v r = __builtin_amdgcn_permlane32_swap(c.u, c.u, false, false);
    union { unsigned u; float f; } a, b; a.u = r[0]; b.u = r[1];
    return a.f + b.f;
}
#else
#define HAVE_PERMLANE 0
__device__ __forceinline__ float red16_max(float x) { return fmaxf(x, __shfl_xor(x, 16)); }
__device__ __forceinline__ float red32_max(float x) { return fmaxf(x, __shfl_xor(x, 32)); }
__device__ __forceinline__ float red16_sum(float x) { return x + __shfl_xor(x, 16); }
__device__ __forceinline__ float red32_sum(float x) { return x + __shfl_xor(x, 32); }
#endif

// load 8 consecutive f32 and convert to f16x8 fragment (RTN)
__device__ __forceinline__ half8 ld_f32_as_h8(const float* p) {
    f32x4 a = *(const f32x4*)(p);
    f32x4 b = *(const f32x4*)(p + 4);
    half8 w;
    #pragma unroll
    for (int j = 0; j < 4; ++j) {
        w[j] = (_Float16)a[j];
        w[4 + j] = (_Float16)b[j];
    }
    return w;
}

// -------- kernel 1: projections, single f16 MFMA, W converted in-register ---
// (R21-proven) 256 blocks x 4 waves; wave w handles jt in {2w, 2w+1}.
// Q pre-scaled by log2(e) so flash softmax runs in exp2 domain.
__global__ __launch_bounds__(256) void proj_kernel(
    const float* __restrict__ X, const float* __restrict__ Wq,
    const float* __restrict__ Wk, const float* __restrict__ Wv,
    ushort* __restrict__ Qh, ushort* __restrict__ Kh, ushort* __restrict__ Vt) {
    const int tid = threadIdx.x;
    const int lane = tid & 63;
    const int wid = tid >> 6;
    const int g = lane >> 4, r16 = lane & 15;
    const int qbase = blockIdx.x * 32;

    half8 xf[2][4];
    #pragma unroll
    for (int qa = 0; qa < 2; ++qa) {
        const float* xr = X + (size_t)(qbase + 16 * qa + r16) * D + 8 * g;
        #pragma unroll
        for (int ds = 0; ds < 4; ++ds)
            xf[qa][ds] = ld_f32_as_h8(xr + 32 * ds);
    }

    #pragma unroll
    for (int m = 0; m < 2; ++m) {
        const float* W = m ? Wk : Wq;
        ushort* O = m ? Kh : Qh;
        const float sc = m ? 1.0f : LOG2E;
        #pragma unroll
        for (int jj = 0; jj < 2; ++jj) {
            int jt = 2 * wid + jj;
            const float* wr = W + (size_t)(16 * jt + r16) * D + 8 * g;
            f32x4 acc[2] = {zero4(), zero4()};
            #pragma unroll
            for (int ds = 0; ds < 4; ++ds) {
                half8 wf = ld_f32_as_h8(wr + 32 * ds);
                #pragma unroll
                for (int qa = 0; qa < 2; ++qa)
                    acc[qa] = __builtin_amdgcn_mfma_f32_16x16x32_f16(wf, xf[qa][ds], acc[qa], 0, 0, 0);
            }
            #pragma unroll
            for (int qa = 0; qa < 2; ++qa) {
                half4 pk;
                #pragma unroll
                for (int r = 0; r < 4; ++r) pk[r] = (_Float16)(acc[qa][r] * sc);
                *(half4*)(O + (size_t)(qbase + 16 * qa + r16) * D + 16 * jt + 4 * g) = pk;
            }
        }
    }
    {
        #pragma unroll
        for (int jj = 0; jj < 2; ++jj) {
            int jt = 2 * wid + jj;
            const float* wr = Wv + (size_t)(16 * jt + r16) * D + 8 * g;
            f32x4 acc[2] = {zero4(), zero4()};
            #pragma unroll
            for (int ds = 0; ds < 4; ++ds) {
                half8 wf = ld_f32_as_h8(wr + 32 * ds);
                #pragma unroll
                for (int qa = 0; qa < 2; ++qa)
                    acc[qa] = __builtin_amdgcn_mfma_f32_16x16x32_f16(xf[qa][ds], wf, acc[qa], 0, 0, 0);
            }
            #pragma unroll
            for (int qa = 0; qa < 2; ++qa) {
                half4 pk;
                #pragma unroll
                for (int r = 0; r < 4; ++r) pk[r] = (_Float16)acc[qa][r];
                *(half4*)(Vt + (size_t)(16 * jt + r16) * N_TOK + qbase + 16 * qa + 4 * g) = pk;
            }
        }
    }
}

// -------- kernel 2: flash attention, K+V LDS dbuf, P in registers -----------
// R24 base (setprio, permlane reduces, deferred l, peeled loop) with the P
// LDS round-trip replaced by an exact in-register permlane exchange:
//   x=S[2c][h], y=S[2c+1][h];
//   (A0,A1)=permlane32_swap(x,y): A0=(x0,x1,y0,y1) rows, A1=(x2,x3,y2,y3)
//   (B0,B1)=permlane16_swap(A0,A1): B0=(x0,x2,y0,y2)=pf dword(p=0),
//                                   B1=(x1,x3,y1,y3)=pf dword(p=1)
// Source quad (g',t) holds P[k=16t+4g'+r][q=r16]; target B-frag needs
// k=32c+8g+j -> t=2c+(g>>1), g'=2(g&1)+(j>>2), r=j&3 -- exactly the rows
// the two swaps deliver. Removes 12 LDS ops/iter + P_lds (LDS 80->64KB).
// launch_bounds(256) (no min-wave cap): avoids the 128-VGPR spill cliff;
// occupancy stays LDS-bound at 2 blocks/CU.
template<int NS>
__global__ __launch_bounds__(256) void flash_kernel(
    const ushort* __restrict__ Qh, const ushort* __restrict__ Kh,
    const ushort* __restrict__ Vt, ushort* __restrict__ Opb, float* __restrict__ ML) {
    __shared__ __align__(16) ushort K_lds[2][KVB * D];   // 2 x 16 KB f16
    __shared__ __align__(16) ushort V_lds[2][D * KVB];   // 2 x 16 KB f16

    const int tid = threadIdx.x;
    const int lane = tid & 63;
    const int wid = tid >> 6;
    const int g = lane >> 4, r16 = lane & 15;
    const int sp = blockIdx.x % NS;        // == XCD id when NS==8
    const int qg = blockIdx.x / NS;
    const int nIter = KVTILES / NS;        // compile-time (KVTILES % NS == 0)
    const int t0 = sp * nIter;
    const int qbase = qg * 128 + wid * 32;

    half8 qf[2][4];
    #pragma unroll
    for (int qa = 0; qa < 2; ++qa) {
        const ushort* qr = Qh + (size_t)(qbase + 16 * qa + r16) * D + 8 * g;
        #pragma unroll
        for (int ds = 0; ds < 4; ++ds)
            qf[qa][ds] = *(const half8*)(qr + 32 * ds);
    }

    float m[2] = {-INFINITY, -INFINITY}, l[2] = {0.f, 0.f};   // l: per-LANE partial
    f32x4 o[2][8];
    #pragma unroll
    for (int qa = 0; qa < 2; ++qa)
        #pragma unroll
        for (int dt = 0; dt < 8; ++dt) o[qa][dt] = zero4();

    short8 sk[4], sv[4];

    auto LOADT = [&](int it) {
        const int kv = it * KVB;
        #pragma unroll
        for (int rr = 0; rr < 4; ++rr) {
            int idx = tid + 256 * rr;              // [0,1024)
            int row = idx >> 4, seg = idx & 15;
            sk[rr] = *(const short8*)(Kh + (size_t)(kv + row) * D + seg * 8);
        }
        #pragma unroll
        for (int rr = 0; rr < 4; ++rr) {
            int idx = tid + 256 * rr;              // [0,1024)
            int row = idx >> 3, seg = idx & 7;
            sv[rr] = *(const short8*)(Vt + (size_t)row * N_TOK + kv + seg * 8);
        }
    };
    auto WRITET = [&](int b) {
        #pragma unroll
        for (int rr = 0; rr < 4; ++rr) {
            int idx = tid + 256 * rr;
            int row = idx >> 4, seg = idx & 15;
            *(short8*)&K_lds[b][(row * 128 + seg * 8) ^ ((row & 7) << 3)] = sk[rr];
        }
        #pragma unroll
        for (int rr = 0; rr < 4; ++rr) {
            int idx = tid + 256 * rr;
            int row = idx >> 3, seg = idx & 7;
            *(short8*)&V_lds[b][(row * 64 + seg * 8) ^ ((row & 7) << 3)] = sv[rr];
        }
    };

    auto COMPUTE = [&](int b) {
        const ushort* kb = K_lds[b];
        const ushort* vb = V_lds[b];

        // ---- S^T = K*Q^T (scores in log2 domain via Q pre-scaling)
        f32x4 s[2][4];
        #pragma unroll
        for (int qa = 0; qa < 2; ++qa)
            #pragma unroll
            for (int t = 0; t < 4; ++t) s[qa][t] = zero4();
        __builtin_amdgcn_s_setprio(1);
        #pragma unroll
        for (int t = 0; t < 4; ++t) {
            #pragma unroll
            for (int ds = 0; ds < 4; ++ds) {
                int row = 16 * t + r16;
                half8 kf = *(const half8*)&kb[(row * 128 + 32 * ds + 8 * g) ^ ((row & 7) << 3)];
                #pragma unroll
                for (int qa = 0; qa < 2; ++qa)
                    s[qa][t] = __builtin_amdgcn_mfma_f32_16x16x32_f16(kf, qf[qa][ds], s[qa][t], 0, 0, 0);
            }
        }
        __builtin_amdgcn_s_setprio(0);

        // ---- online softmax + in-register P exchange (no LDS)
        half8 pfr[2][2];   // [qa][c]: PV B-fragments, built via permlane
        #pragma unroll
        for (int qa = 0; qa < 2; ++qa) {
            float tm = max16(s[qa]);
            tm = red16_max(tm);
            tm = red32_max(tm);
            // exact-skip rescale: when no lane's max grew, scale==1 for all
            if (!__all(tm <= m[qa])) {
                float mnew = fmaxf(m[qa], tm);
                float scale = ex2(m[qa] - mnew);
                l[qa] *= scale;       // lane-partial rescales identically
                #pragma unroll
                for (int dt = 0; dt < 8; ++dt) o[qa][dt] *= scale;
                m[qa] = mnew;
            }
            float psum = 0.f;
            #pragma unroll
            for (int c2 = 0; c2 < 2; ++c2) {
                unsigned sd[2][2];   // [tt][h] pkrtz dwords for t=2c2+tt
                #pragma unroll
                for (int tt = 0; tt < 2; ++tt) {
                    int t = 2 * c2 + tt;
                    float p0 = ex2(s[qa][t][0] - m[qa]);
                    float p1 = ex2(s[qa][t][1] - m[qa]);
                    float p2 = ex2(s[qa][t][2] - m[qa]);
                    float p3 = ex2(s[qa][t][3] - m[qa]);
                    psum += (p0 + p1) + (p2 + p3);
                    union { fp16x2 h; unsigned u; } u0, u1;
                    u0.h = __builtin_amdgcn_cvt_pkrtz(p0, p1);
                    u1.h = __builtin_amdgcn_cvt_pkrtz(p2, p3);
                    sd[tt][0] = u0.u;
                    sd[tt][1] = u1.u;
                }
#if HAVE_PERMLANE
                union { unsigned u[4]; half8 h; } pf;
                #pragma unroll
                for (int h = 0; h < 2; ++h) {
                    uint2v A = __builtin_amdgcn_permlane32_swap(sd[0][h], sd[1][h], false, false);
                    uint2v B = __builtin_amdgcn_permlane16_swap(A[0], A[1], false, false);
                    pf.u[0 + h] = B[0];   // p=0 half (j=0..3)
                    pf.u[2 + h] = B[1];   // p=1 half (j=4..7)
                }
                pfr[qa][c2] = pf.h;
#else
                // fallback: shfl-based exchange (same mapping)
                union { unsigned u[4]; half8 h; } pf;
                #pragma unroll
                for (int u = 0; u < 4; ++u) {
                    int src_g = 2 * (g & 1) + (u >> 1);
                    int src_t_sel = (g >> 1);          // tt within this c2
                    unsigned v0 = __shfl(sd[0][u & 1], src_g * 16 + r16);
                    unsigned v1 = __shfl(sd[1][u & 1], src_g * 16 + r16);
                    pf.u[u] = src_t_sel ? v1 : v0;
                }
                pfr[qa][c2] = pf.h;
#endif
            }
            l[qa] += psum;            // no cross-lane reduce here (epilogue)
        }

        // ---- O^T += V^T * P^T : 2 kv-chunks x 8 d-tiles (f16, P from regs)
        __builtin_amdgcn_s_setprio(1);
        #pragma unroll
        for (int c = 0; c < 2; ++c) {
            #pragma unroll
            for (int dt = 0; dt < 8; ++dt) {
                int row = 16 * dt + r16;
                half8 vf = *(const half8*)&vb[(row * 64 + 32 * c + 8 * g) ^ ((row & 7) << 3)];
                o[0][dt] = __builtin_amdgcn_mfma_f32_16x16x32_f16(vf, pfr[0][c], o[0][dt], 0, 0, 0);
                o[1][dt] = __builtin_amdgcn_mfma_f32_16x16x32_f16(vf, pfr[1][c], o[1][dt], 0, 0, 0);
            }
        }
        __builtin_amdgcn_s_setprio(0);
    };

    LOADT(t0);
    WRITET(0);
    __syncthreads();

    int buf = 0;
    for (int ii = 0; ii < nIter - 1; ++ii) {   // hot loop: no guards
        LOADT(t0 + ii + 1);
        COMPUTE(buf);
        WRITET(buf ^ 1);
        __syncthreads();
        buf ^= 1;
    }
    COMPUTE(buf);                              // peeled final iteration

    // ---- epilogue: partial O (pre-division, f16) + (m[log2], l reduced once)
    #pragma unroll
    for (int qa = 0; qa < 2; ++qa) {
        float lt = red32_sum(red16_sum(l[qa]));
        ushort* obase = Opb + ((size_t)sp * N_TOK + qbase + 16 * qa + r16) * D + 4 * g;
        #pragma unroll
        for (int dt = 0; dt < 8; ++dt) {
            half4 pk;
            #pragma unroll
            for (int r = 0; r < 4; ++r) pk[r] = (_Float16)o[qa][dt][r];
            *(half4*)(obase + 16 * dt) = pk;
        }
        if (g == 0) {
            int qt = (qbase + 16 * qa) >> 4;
            float* ml = ML + ((size_t)sp * QTILES + qt) * 32;
            ml[r16] = m[qa];
            ml[16 + r16] = lt;
        }
    }
}

// -------- kernel 3: merge the NS KV-split partials (16B loads, 8 elem/thr) --
template<int NS>
__global__ void merge_kernel(const ushort* __restrict__ Opb, const float* __restrict__ ML,
                             float* __restrict__ out) {
    int i = blockIdx.x * blockDim.x + threadIdx.x;
    int e = i * 8;
    if (e >= N_TOK * D) return;
    int q = e >> 7;
    int qt = q >> 4, qr = q & 15;
    float mv[NS], lv[NS];
    float M = -INFINITY;
    #pragma unroll
    for (int s = 0; s < NS; ++s) {
        const float* ml = ML + ((size_t)s * QTILES + qt) * 32;
        mv[s] = ml[qr];
        lv[s] = ml[16 + qr];
        M = fmaxf(M, mv[s]);
    }
    float L = 0.f, a[NS];
    #pragma unroll
    for (int s = 0; s < NS; ++s) { a[s] = __builtin_amdgcn_exp2f(mv[s] - M); L += a[s] * lv[s]; }
    float inv = 1.f / L;
    float acc[8];
    #pragma unroll
    for (int r = 0; r < 8; ++r) acc[r] = 0.f;
    #pragma unroll
    for (int s = 0; s < NS; ++s) {
        half8 ov = *(const half8*)(Opb + (size_t)s * N_TOK * D + e);
        #pragma unroll
        for (int r = 0; r < 8; ++r) acc[r] += (float)ov[r] * a[s];
    }
    f32x4 o0, o1;
    #pragma unroll
    for (int r = 0; r < 4; ++r) { o0[r] = acc[r] * inv; o1[r] = acc[4 + r] * inv; }
    *(f32x4*)(out + e) = o0;
    *(f32x4*)(out + e + 4) = o1;
}

extern "C" void kernel_launch(void* const* d_in, const int* in_sizes, int n_in,
                              void* d_out, int out_size, void* d_ws, size_t ws_size,
                              hipStream_t stream) {
    const float* X  = (const float*)d_in[0];
    const float* Wq = (const float*)d_in[1];
    const float* Wk = (const float*)d_in[2];
    const float* Wv = (const float*)d_in[3];
    float* out = (float*)d_out;

    char* ws = (char*)d_ws;
    ushort* Qh  = (ushort*)(ws);                   // 2 MB (f16, pre-scaled log2e)
    ushort* Kh  = (ushort*)(ws + 2097152);         // 2 MB (f16)
    ushort* Vt  = (ushort*)(ws + 4194304);         // 2 MB (f16, transposed)
    ushort* Opb = (ushort*)(ws + 6291456);         // NS * 2 MB (f16 partials)

    const size_t op_off = 6291456;
    const size_t need8 = op_off + (size_t)8 * N_TOK * D * 2 + (size_t)8 * QTILES * 32 * 4;

    proj_kernel<<<256, 256, 0, stream>>>(X, Wq, Wk, Wv, Qh, Kh, Vt);

    if (ws_size >= need8) {
        float* ML = (float*)(ws + op_off + (size_t)8 * N_TOK * D * 2);
        flash_kernel<8><<<(N_TOK / 128) * 8, 256, 0, stream>>>(Qh, Kh, Vt, Opb, ML);
        merge_kernel<8><<<(N_TOK * D / 8 + 255) / 256, 256, 0, stream>>>(Opb, ML, out);
    } else {
        float* ML = (float*)(ws + op_off + (size_t)4 * N_TOK * D * 2);
        flash_kernel<4><<<(N_TOK / 128) * 4, 256, 0, stream>>>(Qh, Kh, Vt, Opb, ML);
        merge_kernel<4><<<(N_TOK * D / 8 + 255) / 256, 256, 0, stream>>>(Opb, ML, out);
    }
}